// Round 20
// baseline (51.222 us; speedup 1.0000x reference)
//
#include <hip/hip_runtime.h>

#define C 128
#define DEG 32
#define NPIECES 5

typedef __fp16 h2 __attribute__((ext_vector_type(2)));

// ---- CAS via explicit packed-f16 min/max (v_pk_*, 2 inst) ----
__device__ __forceinline__ void cas_desc(h2& a, h2& b) {
    h2 mx, mn;
    asm("v_pk_max_f16 %0, %2, %3\n\t"
        "v_pk_min_f16 %1, %2, %3"
        : "=&v"(mx), "=v"(mn)
        : "v"(a), "v"(b));
    a = mx;
    b = mn;
}

// ---- Batcher odd-even mergesort, compile-time generated (191 CAS, n=32) ----
template<int I, int END, int R, int M>
__device__ __forceinline__ void oe_merge_loop(h2* v) {
    if constexpr (I + R < END) {
        cas_desc(v[I], v[I + R]);
        oe_merge_loop<I + M, END, R, M>(v);
    }
}
template<int LO, int N, int R>
__device__ __forceinline__ void oe_merge(h2* v) {
    constexpr int M = R * 2;
    if constexpr (M < N) {
        oe_merge<LO, N, M>(v);
        oe_merge<LO + R, N, M>(v);
        oe_merge_loop<LO + R, LO + N, R, M>(v);
    } else {
        cas_desc(v[LO], v[LO + R]);
    }
}
template<int LO, int N>
__device__ __forceinline__ void oe_sort(h2* v) {
    if constexpr (N > 1) {
        constexpr int M = N / 2;
        oe_sort<LO, M>(v);
        oe_sort<LO + M, M>(v);
        oe_merge<LO, N, 1>(v);
    }
}

#define REP32(M) M(0) M(1) M(2) M(3) M(4) M(5) M(6) M(7) M(8) M(9) M(10) M(11) \
 M(12) M(13) M(14) M(15) M(16) M(17) M(18) M(19) M(20) M(21) M(22) M(23) \
 M(24) M(25) M(26) M(27) M(28) M(29) M(30) M(31)

// Non-volatile bulk pin: all 32 values live here (blocks remat/re-gather)
// without serializing load issue.
#define PIN_ALL \
    asm("" : "+v"(v[0]),"+v"(v[1]),"+v"(v[2]),"+v"(v[3]),"+v"(v[4]),"+v"(v[5]), \
             "+v"(v[6]),"+v"(v[7]),"+v"(v[8]),"+v"(v[9]),"+v"(v[10]),"+v"(v[11]), \
             "+v"(v[12]),"+v"(v[13]),"+v"(v[14]),"+v"(v[15])); \
    asm("" : "+v"(v[16]),"+v"(v[17]),"+v"(v[18]),"+v"(v[19]),"+v"(v[20]), \
             "+v"(v[21]),"+v"(v[22]),"+v"(v[23]),"+v"(v[24]),"+v"(v[25]), \
             "+v"(v[26]),"+v"(v[27]),"+v"(v[28]),"+v"(v[29]),"+v"(v[30]),"+v"(v[31]));

// Gather i: row DWORD-base from per-wave LDS table (padded: entry (q,i) at
// rows[wid][q*33+i] -> distinct banks, 16-lane broadcast, conflict-free).
#define GATH16(i) { \
    int _rb = rw[qpad + (i)]; \
    v[i] = __builtin_bit_cast(h2, x16g[(unsigned)_rb + c2l]); }

// f32 fallback: row base = _rb*8 floats (=col*128), channel pair = 2*c2l.
#define GATH32(i) { \
    int _rb = rw[qpad + (i)]; \
    float2 _f = *(const float2*)(xg + (unsigned)_rb * 8 + 2 * c2l); \
    v[i] = __builtin_amdgcn_cvt_pkrtz(_f.x, _f.y); }

// Weights hoisted to registers once per wave-program (loop-invariant).
#define LDW(i)  const h2 W##i = wh[i][c2l];
#define ACCM(i) _acc += v[i] * W##i;

// ---- prepass v3: x (f32) -> packed f16, GROUP-MAJOR layout, XCD-aligned
// (g = blockIdx&3, grid multiple of 8 — same mapping as fspool, so each
// group slice is left dirty in exactly the L2s that later read it).
// float4 reads / uint2 writes: half the instructions of v2.
__global__ __launch_bounds__(256) void cvt_kernel(
    const float* __restrict__ x, unsigned* __restrict__ x16, int N)
{
    const int g = blockIdx.x & 3;
    const int tid = threadIdx.x;
    const int cq = tid & 7;                      // channel quad within group (0..7)
    const int nl = tid >> 3;                     // node slot within block (0..31)
    const int nb = blockIdx.x >> 2;              // block index within group
    const int stride = (gridDim.x >> 2) * 32;    // nodes per group-pass
    uint2* dst = (uint2*)(x16 + (size_t)g * N * 16);
    const float* src = x + g * 32;

    for (int node = nb * 32 + nl; node < N; node += stride) {
        float4 f = *(const float4*)(src + (size_t)node * C + 4 * cq);
        uint2 u = make_uint2(
            __builtin_bit_cast(unsigned, __builtin_amdgcn_cvt_pkrtz(f.x, f.y)),
            __builtin_bit_cast(unsigned, __builtin_amdgcn_cvt_pkrtz(f.z, f.w)));
        dst[node * 8 + cq] = u;
    }
}

template <bool F16>
__global__ __launch_bounds__(256, 6) void fspool_kernel(
    const float* __restrict__ x,
    const unsigned* __restrict__ x16,
    const int* __restrict__ col,
    const float* __restrict__ weight,
    float* __restrict__ out,
    int N, int wpg)
{
    // 4-way channel split: g = blockIdx&3 (XCD = blockIdx%8 round-robin ->
    // each XCD's L2 caches one 1.28 MB group slice of x16).
    const int g = blockIdx.x & 3;
    __shared__ h2 wh[DEG][16];       // 2 KB: packed w[j][channel-pair] for group
    __shared__ int rows[4][134];     // per-wave padded row-offset tables

    const int tid = threadIdx.x;
    for (int p = tid; p < DEG * 16; p += 256) {
        int j = p >> 4, cp = p & 15;
        int c0 = g * 32 + 2 * cp;
        float t = (float)j / 31.0f;                 // n==32 for every node
        float index = (float)NPIECES * fminf(t, 1.0f);
        float fidx = floorf(index);
        int idx = (int)fidx;
        float frac = index - fidx;
        int idx2 = (idx + 1 > NPIECES) ? NPIECES : (idx + 1);
        float w0 = (1.0f - frac) * weight[c0 * (NPIECES + 1) + idx]
                 + frac         * weight[c0 * (NPIECES + 1) + idx2];
        float w1 = (1.0f - frac) * weight[(c0 + 1) * (NPIECES + 1) + idx]
                 + frac         * weight[(c0 + 1) * (NPIECES + 1) + idx2];
        wh[j][cp] = __builtin_amdgcn_cvt_pkrtz(w0, w1);
    }
    __syncthreads();                 // wh ready; rest is barrier-free

    const int lane = tid & 63;
    const int wid  = tid >> 6;
    const int c2l  = lane & 15;                  // channel pair within group
    const int q    = lane >> 4;                  // node slot within quad (0..3)
    const int qpad = q * 33;                     // padded LDS row-table base
    int* rw = rows[wid];
    // write side of padded table: lane l holds entry l -> [l/32*33 + l%32]
    const int wpad0 = (lane >> 5) * 33 + (lane & 31);

    // Hoist this lane's 32 weights into registers (loop-invariant).
    REP32(LDW)

    const int wig = (blockIdx.x >> 2) * 4 + wid; // wave index within group
    const int nquads = (N + 3) >> 2;
    const unsigned* x16g = x16 + (size_t)g * N * 16;   // f16: 16 dwords/node
    const float*    xg   = x + g * 32;                 // f32 fallback slice

    // Loop with col prefetch (R14 structure, best measured).
    int quad = wig;
    int cr0, cr1;
    if (quad < nquads) {
        int ce = quad * 128 + lane;
        cr0 = col[ce];
        cr1 = col[ce + 64];
    }

    for (; quad < nquads; quad += wpg) {
        rw[wpad0]      = cr0 * 16;   // dword offset of row slice
        rw[66 + wpad0] = cr1 * 16;   // entries 64..127 -> q=2,3

        int nq = quad + wpg;         // prefetch next quad's col entries
        if (nq < nquads) {
            int ce = nq * 128 + lane;
            cr0 = col[ce];
            cr1 = col[ce + 64];
        }

        int node = quad * 4 + q;

        h2 v[32];
        if constexpr (F16) {
            REP32(GATH16)
        } else {
            REP32(GATH32)
        }
        PIN_ALL
        oe_sort<0, 32>(v);           // Batcher: 191 CAS, v_pk_max/min_f16
        h2 _acc; _acc[0] = (__fp16)0.f; _acc[1] = (__fp16)0.f;
        REP32(ACCM)
        if (node < N)
            *(float2*)(out + (size_t)node * C + g * 32 + 2 * c2l) =
                make_float2((float)_acc[0], (float)_acc[1]);
    }
}

extern "C" void kernel_launch(void* const* d_in, const int* in_sizes, int n_in,
                              void* d_out, int out_size, void* d_ws, size_t ws_size,
                              hipStream_t stream) {
    const float* x      = (const float*)d_in[0];
    const int*   edge   = (const int*)d_in[1];
    const float* weight = (const float*)d_in[2];
    float*       out    = (float*)d_out;

    int N = in_sizes[0] / C;       // 20000
    int E = in_sizes[1] / 2;       // 640000
    const int* col = edge + E;     // edge_index[1]

    // 2504 blocks (multiple of 8), 2504 waves/group, 5000 quads ->
    // 2 quads for most waves.
    const int grid = 2504;
    const int wpg  = grid;

    const size_t need = (size_t)N * (C / 2) * sizeof(unsigned);  // 5.12 MB
    if (ws_size >= need) {
        unsigned* x16 = (unsigned*)d_ws;
        // cvt grid: multiple of 8, XCD-aligned with fspool's group mapping.
        cvt_kernel<<<1024, 256, 0, stream>>>(x, x16, N);
        fspool_kernel<true><<<grid, 256, 0, stream>>>(x, x16, col, weight, out, N, wpg);
    } else {
        fspool_kernel<false><<<grid, 256, 0, stream>>>(x, nullptr, col, weight, out, N, wpg);
    }
}

// Round 21
// 36.061 us; speedup vs baseline: 1.4204x; 1.4204x over previous
//
#include <hip/hip_runtime.h>

#define C 128
#define DEG 32
#define NPIECES 5

typedef __fp16 h2 __attribute__((ext_vector_type(2)));

// ---- CAS via explicit packed-f16 min/max (v_pk_*, 2 inst) ----
__device__ __forceinline__ void cas_desc(h2& a, h2& b) {
    h2 mx, mn;
    asm("v_pk_max_f16 %0, %2, %3\n\t"
        "v_pk_min_f16 %1, %2, %3"
        : "=&v"(mx), "=v"(mn)
        : "v"(a), "v"(b));
    a = mx;
    b = mn;
}

// ---- Batcher odd-even mergesort, compile-time generated (191 CAS, n=32) ----
template<int I, int END, int R, int M>
__device__ __forceinline__ void oe_merge_loop(h2* v) {
    if constexpr (I + R < END) {
        cas_desc(v[I], v[I + R]);
        oe_merge_loop<I + M, END, R, M>(v);
    }
}
template<int LO, int N, int R>
__device__ __forceinline__ void oe_merge(h2* v) {
    constexpr int M = R * 2;
    if constexpr (M < N) {
        oe_merge<LO, N, M>(v);
        oe_merge<LO + R, N, M>(v);
        oe_merge_loop<LO + R, LO + N, R, M>(v);
    } else {
        cas_desc(v[LO], v[LO + R]);
    }
}
template<int LO, int N>
__device__ __forceinline__ void oe_sort(h2* v) {
    if constexpr (N > 1) {
        constexpr int M = N / 2;
        oe_sort<LO, M>(v);
        oe_sort<LO + M, M>(v);
        oe_merge<LO, N, 1>(v);
    }
}

#define REP32(M) M(0) M(1) M(2) M(3) M(4) M(5) M(6) M(7) M(8) M(9) M(10) M(11) \
 M(12) M(13) M(14) M(15) M(16) M(17) M(18) M(19) M(20) M(21) M(22) M(23) \
 M(24) M(25) M(26) M(27) M(28) M(29) M(30) M(31)

// Non-volatile bulk pin: all 32 values live here (blocks remat/re-gather)
// without serializing load issue.
#define PIN_ALL \
    asm("" : "+v"(v[0]),"+v"(v[1]),"+v"(v[2]),"+v"(v[3]),"+v"(v[4]),"+v"(v[5]), \
             "+v"(v[6]),"+v"(v[7]),"+v"(v[8]),"+v"(v[9]),"+v"(v[10]),"+v"(v[11]), \
             "+v"(v[12]),"+v"(v[13]),"+v"(v[14]),"+v"(v[15])); \
    asm("" : "+v"(v[16]),"+v"(v[17]),"+v"(v[18]),"+v"(v[19]),"+v"(v[20]), \
             "+v"(v[21]),"+v"(v[22]),"+v"(v[23]),"+v"(v[24]),"+v"(v[25]), \
             "+v"(v[26]),"+v"(v[27]),"+v"(v[28]),"+v"(v[29]),"+v"(v[30]),"+v"(v[31]));

// Gather i: row DWORD-base from per-wave LDS table (padded: entry (q,i) at
// rows[wid][q*33+i] -> distinct banks, 16-lane broadcast, conflict-free).
#define GATH16(i) { \
    int _rb = rw[qpad + (i)]; \
    v[i] = __builtin_bit_cast(h2, x16g[(unsigned)_rb + c2l]); }

// f32 fallback: row base = _rb*8 floats (=col*128), channel pair = 2*c2l.
#define GATH32(i) { \
    int _rb = rw[qpad + (i)]; \
    float2 _f = *(const float2*)(xg + (unsigned)_rb * 8 + 2 * c2l); \
    v[i] = __builtin_amdgcn_cvt_pkrtz(_f.x, _f.y); }

// Weights hoisted to registers once per wave-program (loop-invariant).
#define LDW(i)  const h2 W##i = wh[i][c2l];
#define ACCM(i) _acc += v[i] * W##i;

// ---- prepass: x (f32) -> packed f16, GROUP-MAJOR layout, XCD-aligned
// (g = blockIdx&3, grid multiple of 8 — same mapping as fspool, so each
// group slice is left dirty in exactly the L2s that later read it).
// float4 reads / uint2 writes.
__global__ __launch_bounds__(256) void cvt_kernel(
    const float* __restrict__ x, unsigned* __restrict__ x16, int N)
{
    const int g = blockIdx.x & 3;
    const int tid = threadIdx.x;
    const int cq = tid & 7;                      // channel quad within group (0..7)
    const int nl = tid >> 3;                     // node slot within block (0..31)
    const int nb = blockIdx.x >> 2;              // block index within group
    const int stride = (gridDim.x >> 2) * 32;    // nodes per group-pass
    uint2* dst = (uint2*)(x16 + (size_t)g * N * 16);
    const float* src = x + g * 32;

    for (int node = nb * 32 + nl; node < N; node += stride) {
        float4 f = *(const float4*)(src + (size_t)node * C + 4 * cq);
        uint2 u = make_uint2(
            __builtin_bit_cast(unsigned, __builtin_amdgcn_cvt_pkrtz(f.x, f.y)),
            __builtin_bit_cast(unsigned, __builtin_amdgcn_cvt_pkrtz(f.z, f.w)));
        dst[node * 8 + cq] = u;
    }
}

template <bool F16>
__global__ __launch_bounds__(256, 4) void fspool_kernel(
    const float* __restrict__ x,
    const unsigned* __restrict__ x16,
    const int* __restrict__ col,
    const float* __restrict__ weight,
    float* __restrict__ out,
    int N, int wpg)
{
    // 4-way channel split: g = blockIdx&3 (XCD = blockIdx%8 round-robin ->
    // each XCD's L2 caches one 1.28 MB group slice of x16).
    const int g = blockIdx.x & 3;
    __shared__ h2 wh[DEG][16];       // 2 KB: packed w[j][channel-pair] for group
    __shared__ int rows[4][134];     // per-wave padded row-offset tables

    const int tid = threadIdx.x;
    for (int p = tid; p < DEG * 16; p += 256) {
        int j = p >> 4, cp = p & 15;
        int c0 = g * 32 + 2 * cp;
        float t = (float)j / 31.0f;                 // n==32 for every node
        float index = (float)NPIECES * fminf(t, 1.0f);
        float fidx = floorf(index);
        int idx = (int)fidx;
        float frac = index - fidx;
        int idx2 = (idx + 1 > NPIECES) ? NPIECES : (idx + 1);
        float w0 = (1.0f - frac) * weight[c0 * (NPIECES + 1) + idx]
                 + frac         * weight[c0 * (NPIECES + 1) + idx2];
        float w1 = (1.0f - frac) * weight[(c0 + 1) * (NPIECES + 1) + idx]
                 + frac         * weight[(c0 + 1) * (NPIECES + 1) + idx2];
        wh[j][cp] = __builtin_amdgcn_cvt_pkrtz(w0, w1);
    }
    __syncthreads();                 // wh ready; rest is barrier-free

    const int lane = tid & 63;
    const int wid  = tid >> 6;
    const int c2l  = lane & 15;                  // channel pair within group
    const int q    = lane >> 4;                  // node slot within quad (0..3)
    const int qpad = q * 33;                     // padded LDS row-table base
    int* rw = rows[wid];
    // write side of padded table: lane l holds entry l -> [l/32*33 + l%32]
    const int wpad0 = (lane >> 5) * 33 + (lane & 31);

    // Hoist this lane's 32 weights into registers (loop-invariant).
    REP32(LDW)

    const int wig = (blockIdx.x >> 2) * 4 + wid; // wave index within group
    const int nquads = (N + 3) >> 2;
    const unsigned* x16g = x16 + (size_t)g * N * 16;   // f16: 16 dwords/node
    const float*    xg   = x + g * 32;                 // f32 fallback slice

    // Loop with col prefetch (R14 structure, best measured).
    int quad = wig;
    int cr0, cr1;
    if (quad < nquads) {
        int ce = quad * 128 + lane;
        cr0 = col[ce];
        cr1 = col[ce + 64];
    }

    for (; quad < nquads; quad += wpg) {
        rw[wpad0]      = cr0 * 16;   // dword offset of row slice
        rw[66 + wpad0] = cr1 * 16;   // entries 64..127 -> q=2,3

        int nq = quad + wpg;         // prefetch next quad's col entries
        if (nq < nquads) {
            int ce = nq * 128 + lane;
            cr0 = col[ce];
            cr1 = col[ce + 64];
        }

        int node = quad * 4 + q;

        h2 v[32];
        if constexpr (F16) {
            REP32(GATH16)
        } else {
            REP32(GATH32)
        }
        PIN_ALL
        oe_sort<0, 32>(v);           // Batcher: 191 CAS, v_pk_max/min_f16
        h2 _acc; _acc[0] = (__fp16)0.f; _acc[1] = (__fp16)0.f;
        REP32(ACCM)
        if (node < N)
            *(float2*)(out + (size_t)node * C + g * 32 + 2 * c2l) =
                make_float2((float)_acc[0], (float)_acc[1]);
    }
}

extern "C" void kernel_launch(void* const* d_in, const int* in_sizes, int n_in,
                              void* d_out, int out_size, void* d_ws, size_t ws_size,
                              hipStream_t stream) {
    const float* x      = (const float*)d_in[0];
    const int*   edge   = (const int*)d_in[1];
    const float* weight = (const float*)d_in[2];
    float*       out    = (float*)d_out;

    int N = in_sizes[0] / C;       // 20000
    int E = in_sizes[1] / 2;       // 640000
    const int* col = edge + E;     // edge_index[1]

    // 2504 blocks (multiple of 8), 2504 waves/group, 5000 quads ->
    // 2 quads for most waves.
    const int grid = 2504;
    const int wpg  = grid;

    const size_t need = (size_t)N * (C / 2) * sizeof(unsigned);  // 5.12 MB
    if (ws_size >= need) {
        unsigned* x16 = (unsigned*)d_ws;
        // cvt grid: multiple of 8, XCD-aligned with fspool's group mapping.
        cvt_kernel<<<1024, 256, 0, stream>>>(x, x16, N);
        fspool_kernel<true><<<grid, 256, 0, stream>>>(x, x16, col, weight, out, N, wpg);
    } else {
        fspool_kernel<false><<<grid, 256, 0, stream>>>(x, nullptr, col, weight, out, N, wpg);
    }
}

// Round 22
// 35.829 us; speedup vs baseline: 1.4296x; 1.0065x over previous
//
#include <hip/hip_runtime.h>

#define C 128
#define DEG 32
#define NPIECES 5

typedef __fp16 h2 __attribute__((ext_vector_type(2)));

// ---- CAS via explicit packed-f16 min/max (v_pk_*, 2 inst) ----
__device__ __forceinline__ void cas_desc(h2& a, h2& b) {
    h2 mx, mn;
    asm("v_pk_max_f16 %0, %2, %3\n\t"
        "v_pk_min_f16 %1, %2, %3"
        : "=&v"(mx), "=v"(mn)
        : "v"(a), "v"(b));
    a = mx;
    b = mn;
}

// ---- Batcher odd-even mergesort, compile-time generated (191 CAS, n=32) ----
template<int I, int END, int R, int M>
__device__ __forceinline__ void oe_merge_loop(h2* v) {
    if constexpr (I + R < END) {
        cas_desc(v[I], v[I + R]);
        oe_merge_loop<I + M, END, R, M>(v);
    }
}
template<int LO, int N, int R>
__device__ __forceinline__ void oe_merge(h2* v) {
    constexpr int M = R * 2;
    if constexpr (M < N) {
        oe_merge<LO, N, M>(v);
        oe_merge<LO + R, N, M>(v);
        oe_merge_loop<LO + R, LO + N, R, M>(v);
    } else {
        cas_desc(v[LO], v[LO + R]);
    }
}
template<int LO, int N>
__device__ __forceinline__ void oe_sort(h2* v) {
    if constexpr (N > 1) {
        constexpr int M = N / 2;
        oe_sort<LO, M>(v);
        oe_sort<LO + M, M>(v);
        oe_merge<LO, N, 1>(v);
    }
}

#define REP32(M) M(0) M(1) M(2) M(3) M(4) M(5) M(6) M(7) M(8) M(9) M(10) M(11) \
 M(12) M(13) M(14) M(15) M(16) M(17) M(18) M(19) M(20) M(21) M(22) M(23) \
 M(24) M(25) M(26) M(27) M(28) M(29) M(30) M(31)

// Non-volatile bulk pin: all 32 values live here (blocks remat/re-gather)
// without serializing load issue.
#define PIN_ALL \
    asm("" : "+v"(v[0]),"+v"(v[1]),"+v"(v[2]),"+v"(v[3]),"+v"(v[4]),"+v"(v[5]), \
             "+v"(v[6]),"+v"(v[7]),"+v"(v[8]),"+v"(v[9]),"+v"(v[10]),"+v"(v[11]), \
             "+v"(v[12]),"+v"(v[13]),"+v"(v[14]),"+v"(v[15])); \
    asm("" : "+v"(v[16]),"+v"(v[17]),"+v"(v[18]),"+v"(v[19]),"+v"(v[20]), \
             "+v"(v[21]),"+v"(v[22]),"+v"(v[23]),"+v"(v[24]),"+v"(v[25]), \
             "+v"(v[26]),"+v"(v[27]),"+v"(v[28]),"+v"(v[29]),"+v"(v[30]),"+v"(v[31]));

// Gather i (f32-direct): row base from per-wave LDS table (padded: entry
// (q,i) at rows[wid][q*33+i] -> distinct banks, 16-lane broadcast,
// conflict-free). Each row's group slice x[col*128 + g*32 ..+32] is exactly
// one 128 B cache line -> per-XCD L2 footprint 20000*128B = 2.56 MB.
#define GATH32(i) { \
    int _rb = rw[qpad + (i)]; \
    float2 _f = *(const float2*)(xg + (unsigned)_rb + 2 * c2l); \
    v[i] = __builtin_amdgcn_cvt_pkrtz(_f.x, _f.y); }

// Weights hoisted to registers once per wave-program (loop-invariant).
#define LDW(i)  const h2 W##i = wh[i][c2l];
#define ACCM(i) _acc += v[i] * W##i;

__global__ __launch_bounds__(256, 4) void fspool_kernel(
    const float* __restrict__ x,
    const int* __restrict__ col,
    const float* __restrict__ weight,
    float* __restrict__ out,
    int N, int wpg)
{
    // 4-way channel split: g = blockIdx&3 (XCD = blockIdx%8 round-robin ->
    // each XCD's L2 caches one 2.56 MB line-exact group slice of x).
    const int g = blockIdx.x & 3;
    __shared__ h2 wh[DEG][16];       // 2 KB: packed w[j][channel-pair] for group
    __shared__ int rows[4][134];     // per-wave padded row-offset tables

    const int tid = threadIdx.x;
    for (int p = tid; p < DEG * 16; p += 256) {
        int j = p >> 4, cp = p & 15;
        int c0 = g * 32 + 2 * cp;
        float t = (float)j / 31.0f;                 // n==32 for every node
        float index = (float)NPIECES * fminf(t, 1.0f);
        float fidx = floorf(index);
        int idx = (int)fidx;
        float frac = index - fidx;
        int idx2 = (idx + 1 > NPIECES) ? NPIECES : (idx + 1);
        float w0 = (1.0f - frac) * weight[c0 * (NPIECES + 1) + idx]
                 + frac         * weight[c0 * (NPIECES + 1) + idx2];
        float w1 = (1.0f - frac) * weight[(c0 + 1) * (NPIECES + 1) + idx]
                 + frac         * weight[(c0 + 1) * (NPIECES + 1) + idx2];
        wh[j][cp] = __builtin_amdgcn_cvt_pkrtz(w0, w1);
    }
    __syncthreads();                 // wh ready; rest is barrier-free

    const int lane = tid & 63;
    const int wid  = tid >> 6;
    const int c2l  = lane & 15;                  // channel pair within group
    const int q    = lane >> 4;                  // node slot within quad (0..3)
    const int qpad = q * 33;                     // padded LDS row-table base
    int* rw = rows[wid];
    // write side of padded table: lane l holds entry l -> [l/32*33 + l%32]
    const int wpad0 = (lane >> 5) * 33 + (lane & 31);

    // Hoist this lane's 32 weights into registers (loop-invariant).
    REP32(LDW)

    const int wig = (blockIdx.x >> 2) * 4 + wid; // wave index within group
    const int nquads = (N + 3) >> 2;
    const float* xg = x + g * 32;                // group channel slice

    // Loop with col prefetch (R14 structure, best measured).
    int quad = wig;
    int cr0, cr1;
    if (quad < nquads) {
        int ce = quad * 128 + lane;
        cr0 = col[ce];
        cr1 = col[ce + 64];
    }

    for (; quad < nquads; quad += wpg) {
        rw[wpad0]      = cr0 * C;    // float offset of row
        rw[66 + wpad0] = cr1 * C;    // entries 64..127 -> q=2,3

        int nq = quad + wpg;         // prefetch next quad's col entries
        if (nq < nquads) {
            int ce = nq * 128 + lane;
            cr0 = col[ce];
            cr1 = col[ce + 64];
        }

        int node = quad * 4 + q;

        h2 v[32];
        REP32(GATH32)
        PIN_ALL
        oe_sort<0, 32>(v);           // Batcher: 191 CAS, v_pk_max/min_f16
        h2 _acc; _acc[0] = (__fp16)0.f; _acc[1] = (__fp16)0.f;
        REP32(ACCM)
        if (node < N)
            *(float2*)(out + (size_t)node * C + g * 32 + 2 * c2l) =
                make_float2((float)_acc[0], (float)_acc[1]);
    }
}

extern "C" void kernel_launch(void* const* d_in, const int* in_sizes, int n_in,
                              void* d_out, int out_size, void* d_ws, size_t ws_size,
                              hipStream_t stream) {
    const float* x      = (const float*)d_in[0];
    const int*   edge   = (const int*)d_in[1];
    const float* weight = (const float*)d_in[2];
    float*       out    = (float*)d_out;

    int N = in_sizes[0] / C;       // 20000
    int E = in_sizes[1] / 2;       // 640000
    const int* col = edge + E;     // edge_index[1]

    // 2504 blocks (multiple of 8), 2504 waves/group, 5000 quads ->
    // 2 quads for most waves. No prepass: gather f32 directly (each row's
    // group slice is one 128 B line; per-XCD footprint 2.56 MB < 4 MiB L2).
    const int grid = 2504;
    const int wpg  = grid;

    fspool_kernel<<<grid, 256, 0, stream>>>(x, col, weight, out, N, wpg);
}